// Round 8
// baseline (818.638 us; speedup 1.0000x reference)
//
#include <hip/hip_runtime.h>
#include <math.h>

#define VOCAB 8000
#define BATCH 128
#define TMAX  512
#define DIM   256
#define HID   128
#define G4    512     // 4*HID
#define NCOL  1024    // 2*G4 (both directions)

// --- DPP lane ops: VALU-speed (~4cyc). quad_perm ctrl = sel0|sel1<<2|sel2<<4|sel3<<6.
__device__ __forceinline__ float dpp_xor1(float x) {   // [1,0,3,2] = 0xB1
  int r = __builtin_amdgcn_update_dpp(0, __builtin_bit_cast(int, x),
                                      0xB1, 0xF, 0xF, true);
  return __builtin_bit_cast(float, r);
}
__device__ __forceinline__ float dpp_xor2(float x) {   // [2,3,0,1] = 0x4E
  int r = __builtin_amdgcn_update_dpp(0, __builtin_bit_cast(int, x),
                                      0x4E, 0xF, 0xF, true);
  return __builtin_bit_cast(float, r);
}
__device__ __forceinline__ unsigned dpp_xor1u(unsigned x) {
  return (unsigned)__builtin_amdgcn_update_dpp(0, (int)x, 0xB1, 0xF, 0xF, true);
}
__device__ __forceinline__ unsigned dpp_xor2u(unsigned x) {
  return (unsigned)__builtin_amdgcn_update_dpp(0, (int)x, 0x4E, 0xF, 0xF, true);
}
__device__ __forceinline__ float dpp_bc0(float x) {    // broadcast quad lane 0
  int r = __builtin_amdgcn_update_dpp(0, __builtin_bit_cast(int, x),
                                      0x00, 0xF, 0xF, true);
  return __builtin_bit_cast(float, r);
}
__device__ __forceinline__ float dpp_bc1(float x) {
  int r = __builtin_amdgcn_update_dpp(0, __builtin_bit_cast(int, x),
                                      0x55, 0xF, 0xF, true);
  return __builtin_bit_cast(float, r);
}
__device__ __forceinline__ float dpp_bc2(float x) {
  int r = __builtin_amdgcn_update_dpp(0, __builtin_bit_cast(int, x),
                                      0xAA, 0xF, 0xF, true);
  return __builtin_bit_cast(float, r);
}
__device__ __forceinline__ float dpp_bc3(float x) {
  int r = __builtin_amdgcn_update_dpp(0, __builtin_bit_cast(int, x),
                                      0xFF, 0xF, 0xF, true);
  return __builtin_bit_cast(float, r);
}

// LDS-only barrier: per-step exchange is exclusively through LDS.
__device__ __forceinline__ void bar_lds() {
  asm volatile("s_waitcnt lgkmcnt(0)" ::: "memory");
  __builtin_amdgcn_s_barrier();
}

// ---------------------------------------------------------------------------
// Kernel 1: embW[v][n] = emb[v,:] . W_ih_dir[n,:] + b_ih_dir[n] + b_hh_dir[n]
// ---------------------------------------------------------------------------
__global__ __launch_bounds__(256) void embw_gemm(
    const float* __restrict__ emb,
    const float* __restrict__ Wf, const float* __restrict__ Wb,
    const float* __restrict__ bihf, const float* __restrict__ bhhf,
    const float* __restrict__ bihb, const float* __restrict__ bhhb,
    float* __restrict__ embW) {
  __shared__ float As[32][132];   // k-major, padded stride
  __shared__ float Bs[32][132];
  const int tid = threadIdx.x;
  const int m0 = blockIdx.x * 128;
  const int n0 = blockIdx.y * 128;
  const int tx = tid & 15, ty = tid >> 4;
  const int lrow = tid >> 1;            // 0..127
  const int lseg = (tid & 1) * 16;      // 0 or 16 (k offset)
  const float* Wsrc = (n0 < 512) ? Wf : Wb;
  const int nbase = (n0 < 512) ? n0 : (n0 - 512);

  float acc[8][8];
  #pragma unroll
  for (int i = 0; i < 8; ++i)
    #pragma unroll
    for (int jj = 0; jj < 8; ++jj) acc[i][jj] = 0.f;

  for (int k0 = 0; k0 < 256; k0 += 32) {
    const int gm = m0 + lrow;
    #pragma unroll
    for (int q = 0; q < 4; ++q) {
      float4 v = make_float4(0.f, 0.f, 0.f, 0.f);
      if (gm < VOCAB) v = *(const float4*)(emb + (size_t)gm * 256 + k0 + lseg + 4 * q);
      As[lseg + 4*q + 0][lrow] = v.x;
      As[lseg + 4*q + 1][lrow] = v.y;
      As[lseg + 4*q + 2][lrow] = v.z;
      As[lseg + 4*q + 3][lrow] = v.w;
    }
    #pragma unroll
    for (int q = 0; q < 4; ++q) {
      float4 v = *(const float4*)(Wsrc + (size_t)(nbase + lrow) * 256 + k0 + lseg + 4 * q);
      Bs[lseg + 4*q + 0][lrow] = v.x;
      Bs[lseg + 4*q + 1][lrow] = v.y;
      Bs[lseg + 4*q + 2][lrow] = v.z;
      Bs[lseg + 4*q + 3][lrow] = v.w;
    }
    __syncthreads();
    #pragma unroll
    for (int k = 0; k < 32; ++k) {
      float4 av0 = *(const float4*)&As[k][ty * 8];
      float4 av1 = *(const float4*)&As[k][ty * 8 + 4];
      float4 bv0 = *(const float4*)&Bs[k][tx * 4];
      float4 bv1 = *(const float4*)&Bs[k][64 + tx * 4];
      float a[8]  = {av0.x, av0.y, av0.z, av0.w, av1.x, av1.y, av1.z, av1.w};
      float bb[8] = {bv0.x, bv0.y, bv0.z, bv0.w, bv1.x, bv1.y, bv1.z, bv1.w};
      #pragma unroll
      for (int i = 0; i < 8; ++i)
        #pragma unroll
        for (int jj = 0; jj < 8; ++jj)
          acc[i][jj] += a[i] * bb[jj];
    }
    __syncthreads();
  }

  float bias[8];
  #pragma unroll
  for (int jj = 0; jj < 8; ++jj) {
    int n = n0 + ((jj < 4) ? (tx * 4 + jj) : (64 + tx * 4 + (jj - 4)));
    bias[jj] = (n < 512) ? (bihf[n] + bhhf[n]) : (bihb[n - 512] + bhhb[n - 512]);
  }
  #pragma unroll
  for (int i = 0; i < 8; ++i) {
    int gm = m0 + ty * 8 + i;
    if (gm >= VOCAB) continue;
    float4 v0 = make_float4(acc[i][0] + bias[0], acc[i][1] + bias[1],
                            acc[i][2] + bias[2], acc[i][3] + bias[3]);
    float4 v1 = make_float4(acc[i][4] + bias[4], acc[i][5] + bias[5],
                            acc[i][6] + bias[6], acc[i][7] + bias[7]);
    *(float4*)(embW + (size_t)gm * NCOL + n0 + tx * 4) = v0;
    *(float4*)(embW + (size_t)gm * NCOL + n0 + 64 + tx * 4) = v1;
  }
}

// ---------------------------------------------------------------------------
// Kernel 2: masked LSTM recurrence — R8: TWO BATCHES PER THREAD.
// R7 proved the per-step idle (~1000-1100cyc) is constant vs lockstep wave
// count: waves sharing a barrier cannot fill each other's stalls. The only
// filler is independent work in the SAME instruction stream between the same
// barriers. Weights depend only on dir -> one thread serves batches b0 and
// b1 with the same 128 pinned weights: MAC_A, reduce_A, MAC_B, reduce_B,
// act_A/act_B (independent exp chains), h-writes, ONE barrier per TWO
// pair-steps. Per-pair work is R1-VERBATIM (lessons R2-R7: masked xor1/xor2
// transpose-reduce, quad gate exchange, one exp per lane, shfl emission).
// Grid: 128 blocks (64 b-pairs x 2 dirs); wall is set by the len=512 block
// (394us == 512x1845cyc confirmed that model).
// ---------------------------------------------------------------------------
#define REP8(M) M(0) M(1) M(2) M(3) M(4) M(5) M(6) M(7)
#define REP8G(M,G) M(G,0) M(G,1) M(G,2) M(G,3) M(G,4) M(G,5) M(G,6) M(G,7)

__global__ __launch_bounds__(512)
__attribute__((amdgpu_waves_per_eu(2, 2)))
void lstm_rec(
    const int* __restrict__ pad_seq, const int* __restrict__ lens,
    const float* __restrict__ Whh_f, const float* __restrict__ Whh_b,
    const float* __restrict__ embW, const float* __restrict__ W_lab,
    float* __restrict__ e_part) {
  const int dir = blockIdx.x & 1;
  const int bp  = blockIdx.x >> 1;     // 0..63
  const int b0  = bp;                  // batch A
  const int b1  = bp + 64;             // batch B
  const int tid = threadIdx.x;
  const int j   = tid >> 2;      // hidden unit 0..127
  const int q   = tid & 3;       // K-quarter / gate owner 0..3
  const int parity = q & 1;
  const int half   = (q >> 1) & 1;

  __shared__ float ringA[8][4][36];  // [slot][chunk][32 + 4 pad]
  __shared__ float ringB[8][4][36];
  __shared__ float wls[4][132];      // W_lab cols for MY direction, padded
  __shared__ int   tokA[TMAX];
  __shared__ int   tokB[TMAX];

  tokA[tid] = pad_seq[b0 * TMAX + tid];
  tokB[tid] = pad_seq[b1 * TMAX + tid];
  wls[tid >> 7][tid & 127] = W_lab[(tid >> 7) * DIM + dir * HID + (tid & 127)];
  if (tid < 144) {
    ((float*)ringA)[tid] = 0.f;      // slot 0 = h(-1) = 0
    ((float*)ringB)[tid] = 0.f;
  }

  const int lenA = lens[b0];
  const int lenB = lens[b1];
  const int lenM = (lenA > lenB) ? lenA : lenB;
  const float* __restrict__ Whh = dir ? Whh_b : Whh_f;

  // W_hh: 4 gate rows x 32 cols = 128 pinned scalars (AGPR-resident, proven)
  const float4* wr0 = (const float4*)(Whh + (size_t)(0 * HID + j) * HID + 32 * q);
  const float4* wr1 = (const float4*)(Whh + (size_t)(1 * HID + j) * HID + 32 * q);
  const float4* wr2 = (const float4*)(Whh + (size_t)(2 * HID + j) * HID + 32 * q);
  const float4* wr3 = (const float4*)(Whh + (size_t)(3 * HID + j) * HID + 32 * q);
#define DECLW(G,I)                                                      \
  float w##G##_##I##_0, w##G##_##I##_1, w##G##_##I##_2, w##G##_##I##_3; \
  { float4 t = wr##G[I];                                                \
    w##G##_##I##_0 = t.x; w##G##_##I##_1 = t.y;                         \
    w##G##_##I##_2 = t.z; w##G##_##I##_3 = t.w; }                       \
  asm volatile("" : "+v"(w##G##_##I##_0));                              \
  asm volatile("" : "+v"(w##G##_##I##_1));                              \
  asm volatile("" : "+v"(w##G##_##I##_2));                              \
  asm volatile("" : "+v"(w##G##_##I##_3));
  REP8G(DECLW,0) REP8G(DECLW,1) REP8G(DECLW,2) REP8G(DECLW,3)
#undef DECLW

#define KEEPW(G,I)                                                      \
  asm volatile("" : "+v"(w##G##_##I##_0), "+v"(w##G##_##I##_1),         \
                    "+v"(w##G##_##I##_2), "+v"(w##G##_##I##_3));

  float cAv = 0.f, cBv = 0.f;
  const float ascale = (q == 2) ? 2.f : 1.f;     // tanh(x)=2*sig(2x)-1 for g
  const float* __restrict__ ecol = embW + dir * G4 + (q * HID + j);
  float* __restrict__ epA = e_part + (size_t)(dir * BATCH + b0) * TMAX * 4;
  float* __restrict__ epB = e_part + (size_t)(dir * BATCH + b1) * TMAX * 4;

  bar_lds();

  // batched x@Wih gathers for the next 8 steps, both pairs (ride across
  // lgkm-only barriers; per-use vmcnt(N) waits)
  float xa0, xa1, xa2, xa3, xa4, xa5, xa6, xa7;
  float xb0, xb1, xb2, xb3, xb4, xb5, xb6, xb7;
#define PREA(r) { const int ss = nbase + r; xa##r = 0.f;                \
    if (ss < lenA) {                                                    \
      const int tt = dir ? (lenA - 1 - ss) : ss;                        \
      xa##r = ecol[(size_t)tokA[tt] * NCOL]; } }
#define PREB(r) { const int ss = nbase + r; xb##r = 0.f;                \
    if (ss < lenB) {                                                    \
      const int tt = dir ? (lenB - 1 - ss) : ss;                        \
      xb##r = ecol[(size_t)tokB[tt] * NCOL]; } }
  { const int nbase = 0; REP8(PREA) REP8(PREB) }

#define MACC(G,I)                                         \
    a##G##0 = fmaf(hv##I.x, w##G##_##I##_0, a##G##0);     \
    a##G##1 = fmaf(hv##I.y, w##G##_##I##_1, a##G##1);     \
    a##G##2 = fmaf(hv##I.z, w##G##_##I##_2, a##G##2);     \
    a##G##3 = fmaf(hv##I.w, w##G##_##I##_3, a##G##3);

// One pair-step, R1-verbatim, NO barrier (RING = ringA/ringB, CV = cAv/cBv).
#define STEP1(r, XW, RING, CV, HWSTMT)                                  \
  {                                                                     \
    const float4* h4 = (const float4*)&RING[r][q][0];                   \
    float4 hv0 = h4[0], hv1 = h4[1], hv2 = h4[2], hv3 = h4[3];          \
    float4 hv4 = h4[4], hv5 = h4[5], hv6 = h4[6], hv7 = h4[7];          \
    float a00=0.f,a01=0.f,a02=0.f,a03=0.f;                              \
    float a10=0.f,a11=0.f,a12=0.f,a13=0.f;                              \
    float a20=0.f,a21=0.f,a22=0.f,a23=0.f;                              \
    float a30=0.f,a31=0.f,a32=0.f,a33=0.f;                              \
    REP8G(MACC,0) REP8G(MACC,1) REP8G(MACC,2) REP8G(MACC,3)             \
    const float p0 = (a00+a01)+(a02+a03);                               \
    const float p1 = (a10+a11)+(a12+a13);                               \
    const float p2 = (a20+a21)+(a22+a23);                               \
    const float p3 = (a30+a31)+(a32+a33);                               \
    const float klo = parity ? p1 : p0, slo = parity ? p0 : p1;         \
    const float khi = parity ? p3 : p2, shi = parity ? p2 : p3;         \
    const float alo = klo + dpp_xor1(slo);                              \
    const float ahi = khi + dpp_xor1(shi);                              \
    const float kb = half ? ahi : alo, sb = half ? alo : ahi;           \
    const float tot = kb + dpp_xor2(sb);                                \
    const float aa = tot + (XW);                                        \
    const float sg = 1.f / (1.f + __expf(-ascale * aa));                \
    const float act = (q == 2) ? (2.f * sg - 1.f) : sg;                 \
    const float e1 = dpp_xor1(act);                                     \
    const float e2 = dpp_xor2(act);                                     \
    const float e3 = dpp_xor2(e1);                                      \
    const float ev  = parity ? e1 : act, od  = parity ? act : e1;       \
    const float ev2 = parity ? e3 : e2,  od2 = parity ? e2 : e3;        \
    const float ig = half ? ev2 : ev, fg = half ? od2 : od;             \
    const float gt = half ? ev : ev2, og = half ? od : od2;             \
    CV = fg * CV + ig * gt;                                             \
    const float s2 = 1.f / (1.f + __expf(-2.f * CV));                   \
    const float hh = og * (2.f * s2 - 1.f);                             \
    HWSTMT                                                              \
  }

#define HWA(r) if (q == 0) ringA[((r) + 1) & 7][j >> 5][j & 31] = hh;
#define HWB(r) if (q == 0) ringB[((r) + 1) & 7][j >> 5][j & 31] = hh;

// Fused double-step: A and B bodies back-to-back (independent -> scheduler
// interleaves; B's MACs fill A's tail latency), then ONE barrier.
#define DO(r)                                                           \
  {                                                                     \
    const bool dA = (cntA > r), dB = (cntB > r);  /* block-uniform */   \
    if (dA && dB) { STEP1(r, xa##r, ringA, cAv, HWA(r))                 \
                    STEP1(r, xb##r, ringB, cBv, HWB(r)) }               \
    else if (dA)  { STEP1(r, xa##r, ringA, cAv, HWA(r)) }               \
    else if (dB)  { STEP1(r, xb##r, ringB, cBv, HWB(r)) }               \
    if (dA || dB) bar_lds();                                            \
  }

  for (int s0 = 0; s0 < lenM; s0 += 8) {
    REP8G(KEEPW,0) REP8G(KEEPW,1) REP8G(KEEPW,2) REP8G(KEEPW,3)
    const int remA = lenA - s0, remB = lenB - s0;
    const int cntA = (remA < 0) ? 0 : ((remA < 8) ? remA : 8);
    const int cntB = (remB < 0) ? 0 : ((remB < 8) ? remB : 8);
    DO(0) DO(1) DO(2) DO(3) DO(4) DO(5) DO(6) DO(7)
    // prefetch next group's gathers (no drain: they ride across barriers)
    { const int nbase = s0 + 8; REP8(PREA) REP8(PREB) }
    // emission partials, pair A then pair B: (r,l,sub) = 8x4x16 = 512 thr
    {
      const int r = tid >> 6, l = (tid >> 4) & 3, sub = tid & 15;
      if (r < cntA) {
        const float4* hp = (const float4*)&ringA[(r + 1) & 7][sub >> 2][8 * (sub & 3)];
        const float4 h0 = hp[0], h1 = hp[1];
        const float4* wp = (const float4*)&wls[l][8 * sub];
        const float4 u0 = wp[0], u1 = wp[1];
        float d = h0.x*u0.x + h0.y*u0.y + h0.z*u0.z + h0.w*u0.w
                + h1.x*u1.x + h1.y*u1.y + h1.z*u1.z + h1.w*u1.w;
        d += __shfl_xor(d, 1); d += __shfl_xor(d, 2);
        d += __shfl_xor(d, 4); d += __shfl_xor(d, 8);
        if (sub == 0) {
          const int ss = s0 + r;
          const int tt = dir ? (lenA - 1 - ss) : ss;
          epA[tt * 4 + l] = d;
        }
      }
      if (r < cntB) {
        const float4* hp = (const float4*)&ringB[(r + 1) & 7][sub >> 2][8 * (sub & 3)];
        const float4 h0 = hp[0], h1 = hp[1];
        const float4* wp = (const float4*)&wls[l][8 * sub];
        const float4 u0 = wp[0], u1 = wp[1];
        float d = h0.x*u0.x + h0.y*u0.y + h0.z*u0.z + h0.w*u0.w
                + h1.x*u1.x + h1.y*u1.y + h1.z*u1.z + h1.w*u1.w;
        d += __shfl_xor(d, 1); d += __shfl_xor(d, 2);
        d += __shfl_xor(d, 4); d += __shfl_xor(d, 8);
        if (sub == 0) {
          const int ss = s0 + r;
          const int tt = dir ? (lenB - 1 - ss) : ss;
          epB[tt * 4 + l] = d;
        }
      }
    }
    bar_lds();
  }
#undef DO
#undef HWA
#undef HWB
#undef STEP1
#undef MACC
#undef PREA
#undef PREB
#undef KEEPW
}

// ---------------------------------------------------------------------------
// Kernel 3: Viterbi (emissions pre-reduced into e_part by lstm_rec).
// ---------------------------------------------------------------------------
__global__ __launch_bounds__(512) void viterbi_k(
    const int* __restrict__ lens, const float* __restrict__ e_part,
    const float* __restrict__ b_lab, const float* __restrict__ trans,
    const float* __restrict__ from_BOS, const float* __restrict__ to_EOS,
    int* __restrict__ out) {
  const int b = blockIdx.x;
  const int tid = threadIdx.x;
  __shared__ float sc[TMAX][4];
  __shared__ unsigned btm[TMAX];
  __shared__ int labs[TMAX];
  const int len = lens[b];

  if (tid < len) {
    const float4 f  = *(const float4*)(e_part + ((size_t)b * TMAX + tid) * 4);
    const float4 g2 = *(const float4*)(e_part + ((size_t)(BATCH + b) * TMAX + tid) * 4);
    const float4 bl = *(const float4*)b_lab;
    sc[tid][0] = f.x + g2.x + bl.x;
    sc[tid][1] = f.y + g2.y + bl.y;
    sc[tid][2] = f.z + g2.z + bl.z;
    sc[tid][3] = f.w + g2.w + bl.w;
  }
  __syncthreads();

  // --- DP: lanes 0..3 of wave 0, lane l owns cur-label l ---
  if (tid < 4) {
    const int l = tid;
    float trc0 = trans[0 * 4 + l], trc1 = trans[1 * 4 + l];
    float trc2 = trans[2 * 4 + l], trc3 = trans[3 * 4 + l];
    float best = from_BOS[l] + sc[0][l];
    float e_next = sc[1][l];
    for (int ti = 1; ti < len; ++ti) {
      const float e = e_next;
      e_next = sc[(ti + 1 < TMAX) ? ti + 1 : ti][l];
      const float b0 = dpp_bc0(best);
      const float b1 = dpp_bc1(best);
      const float b2 = dpp_bc2(best);
      const float b3 = dpp_bc3(best);
      // reference add order: (best[p] + e[cur]) + trans[p][cur]; first-max
      float m = (b0 + e) + trc0; int arg = 0;
      float v;
      v = (b1 + e) + trc1; if (v > m) { m = v; arg = 1; }
      v = (b2 + e) + trc2; if (v > m) { m = v; arg = 2; }
      v = (b3 + e) + trc3; if (v > m) { m = v; arg = 3; }
      best = m;
      unsigned av = ((unsigned)arg) << (8 * l);
      av |= dpp_xor1u(av);
      av |= dpp_xor2u(av);
      if (l == 0) btm[ti] = av;
    }
    const float f0 = dpp_bc0(best) + to_EOS[0];
    const float f1 = dpp_bc1(best) + to_EOS[1];
    const float f2 = dpp_bc2(best) + to_EOS[2];
    const float f3 = dpp_bc3(best) + to_EOS[3];
    if (l == 0) {
      float m = f0; int last = 0;
      if (f1 > m) { m = f1; last = 1; }
      if (f2 > m) { m = f2; last = 2; }
      if (f3 > m) { m = f3; last = 3; }
      labs[len - 1] = last;
      int cur = last;
      #pragma unroll 4
      for (int ti = len - 2; ti >= 0; --ti) {
        cur = (int)((btm[ti + 1] >> (8 * cur)) & 255u);
        labs[ti] = cur;
      }
    }
  }
  __syncthreads();
  out[b * TMAX + tid] = (tid < len) ? labs[tid] : 0;
}

// ---------------------------------------------------------------------------
extern "C" void kernel_launch(void* const* d_in, const int* in_sizes, int n_in,
                              void* d_out, int out_size, void* d_ws, size_t ws_size,
                              hipStream_t stream) {
  const int*   pad_seq  = (const int*)d_in[0];
  const int*   lens     = (const int*)d_in[1];
  const float* emb      = (const float*)d_in[2];
  const float* W_ih_f   = (const float*)d_in[3];
  const float* W_hh_f   = (const float*)d_in[4];
  const float* b_ih_f   = (const float*)d_in[5];
  const float* b_hh_f   = (const float*)d_in[6];
  const float* W_ih_b   = (const float*)d_in[7];
  const float* W_hh_b   = (const float*)d_in[8];
  const float* b_ih_b   = (const float*)d_in[9];
  const float* b_hh_b   = (const float*)d_in[10];
  const float* W_lab    = (const float*)d_in[11];
  const float* b_lab    = (const float*)d_in[12];
  const float* trans    = (const float*)d_in[13];
  const float* from_BOS = (const float*)d_in[14];
  const float* to_EOS   = (const float*)d_in[15];
  int* out = (int*)d_out;

  float* embW   = (float*)d_ws;                      // [8000][1024] = 32.8 MB
  float* e_part = embW + (size_t)VOCAB * NCOL;       // [2][B][T][4] = 2 MB

  embw_gemm<<<dim3(63, 8), 256, 0, stream>>>(emb, W_ih_f, W_ih_b,
                                             b_ih_f, b_hh_f, b_ih_b, b_hh_b, embW);
  lstm_rec<<<dim3(128), 512, 0, stream>>>(pad_seq, lens, W_hh_f, W_hh_b,
                                          embW, W_lab, e_part);
  viterbi_k<<<dim3(BATCH), 512, 0, stream>>>(lens, e_part, b_lab, trans,
                                             from_BOS, to_EOS, out);
}

// Round 9
// 575.330 us; speedup vs baseline: 1.4229x; 1.4229x over previous
//
#include <hip/hip_runtime.h>
#include <math.h>

#define VOCAB 8000
#define BATCH 128
#define TMAX  512
#define DIM   256
#define HID   128
#define G4    512     // 4*HID
#define NCOL  1024    // 2*G4 (both directions)

// --- DPP quad-lane ops: VALU-speed (~4cyc) replacements for __shfl within a
// quad. quad_perm ctrl = sel0 | sel1<<2 | sel2<<4 | sel3<<6.
__device__ __forceinline__ float dpp_xor1(float x) {   // [1,0,3,2] = 0xB1
  int r = __builtin_amdgcn_update_dpp(0, __builtin_bit_cast(int, x),
                                      0xB1, 0xF, 0xF, true);
  return __builtin_bit_cast(float, r);
}
__device__ __forceinline__ float dpp_xor2(float x) {   // [2,3,0,1] = 0x4E
  int r = __builtin_amdgcn_update_dpp(0, __builtin_bit_cast(int, x),
                                      0x4E, 0xF, 0xF, true);
  return __builtin_bit_cast(float, r);
}
__device__ __forceinline__ unsigned dpp_xor1u(unsigned x) {
  return (unsigned)__builtin_amdgcn_update_dpp(0, (int)x, 0xB1, 0xF, 0xF, true);
}
__device__ __forceinline__ unsigned dpp_xor2u(unsigned x) {
  return (unsigned)__builtin_amdgcn_update_dpp(0, (int)x, 0x4E, 0xF, 0xF, true);
}
__device__ __forceinline__ float dpp_bc0(float x) {    // broadcast quad lane 0
  int r = __builtin_amdgcn_update_dpp(0, __builtin_bit_cast(int, x),
                                      0x00, 0xF, 0xF, true);
  return __builtin_bit_cast(float, r);
}
__device__ __forceinline__ float dpp_bc1(float x) {
  int r = __builtin_amdgcn_update_dpp(0, __builtin_bit_cast(int, x),
                                      0x55, 0xF, 0xF, true);
  return __builtin_bit_cast(float, r);
}
__device__ __forceinline__ float dpp_bc2(float x) {
  int r = __builtin_amdgcn_update_dpp(0, __builtin_bit_cast(int, x),
                                      0xAA, 0xF, 0xF, true);
  return __builtin_bit_cast(float, r);
}
__device__ __forceinline__ float dpp_bc3(float x) {
  int r = __builtin_amdgcn_update_dpp(0, __builtin_bit_cast(int, x),
                                      0xFF, 0xF, 0xF, true);
  return __builtin_bit_cast(float, r);
}

// LDS-only barrier: the per-step data exchange is exclusively through LDS
// (ring / tok / wls). __syncthreads() would drain vmcnt (token-gather
// prefetch) inside every step; we only need lgkmcnt(0).
__device__ __forceinline__ void bar_lds() {
  asm volatile("s_waitcnt lgkmcnt(0)" ::: "memory");
  __builtin_amdgcn_s_barrier();
}

// ---------------------------------------------------------------------------
// Kernel 1: embW[v][n] = emb[v,:] . W_ih_dir[n,:] + b_ih_dir[n] + b_hh_dir[n]
// ---------------------------------------------------------------------------
__global__ __launch_bounds__(256) void embw_gemm(
    const float* __restrict__ emb,
    const float* __restrict__ Wf, const float* __restrict__ Wb,
    const float* __restrict__ bihf, const float* __restrict__ bhhf,
    const float* __restrict__ bihb, const float* __restrict__ bhhb,
    float* __restrict__ embW) {
  __shared__ float As[32][132];   // k-major, padded stride
  __shared__ float Bs[32][132];
  const int tid = threadIdx.x;
  const int m0 = blockIdx.x * 128;
  const int n0 = blockIdx.y * 128;
  const int tx = tid & 15, ty = tid >> 4;
  const int lrow = tid >> 1;            // 0..127
  const int lseg = (tid & 1) * 16;      // 0 or 16 (k offset)
  const float* Wsrc = (n0 < 512) ? Wf : Wb;
  const int nbase = (n0 < 512) ? n0 : (n0 - 512);

  float acc[8][8];
  #pragma unroll
  for (int i = 0; i < 8; ++i)
    #pragma unroll
    for (int jj = 0; jj < 8; ++jj) acc[i][jj] = 0.f;

  for (int k0 = 0; k0 < 256; k0 += 32) {
    const int gm = m0 + lrow;
    #pragma unroll
    for (int q = 0; q < 4; ++q) {
      float4 v = make_float4(0.f, 0.f, 0.f, 0.f);
      if (gm < VOCAB) v = *(const float4*)(emb + (size_t)gm * 256 + k0 + lseg + 4 * q);
      As[lseg + 4*q + 0][lrow] = v.x;
      As[lseg + 4*q + 1][lrow] = v.y;
      As[lseg + 4*q + 2][lrow] = v.z;
      As[lseg + 4*q + 3][lrow] = v.w;
    }
    #pragma unroll
    for (int q = 0; q < 4; ++q) {
      float4 v = *(const float4*)(Wsrc + (size_t)(nbase + lrow) * 256 + k0 + lseg + 4 * q);
      Bs[lseg + 4*q + 0][lrow] = v.x;
      Bs[lseg + 4*q + 1][lrow] = v.y;
      Bs[lseg + 4*q + 2][lrow] = v.z;
      Bs[lseg + 4*q + 3][lrow] = v.w;
    }
    __syncthreads();
    #pragma unroll
    for (int k = 0; k < 32; ++k) {
      float4 av0 = *(const float4*)&As[k][ty * 8];
      float4 av1 = *(const float4*)&As[k][ty * 8 + 4];
      float4 bv0 = *(const float4*)&Bs[k][tx * 4];
      float4 bv1 = *(const float4*)&Bs[k][64 + tx * 4];
      float a[8]  = {av0.x, av0.y, av0.z, av0.w, av1.x, av1.y, av1.z, av1.w};
      float bb[8] = {bv0.x, bv0.y, bv0.z, bv0.w, bv1.x, bv1.y, bv1.z, bv1.w};
      #pragma unroll
      for (int i = 0; i < 8; ++i)
        #pragma unroll
        for (int jj = 0; jj < 8; ++jj)
          acc[i][jj] += a[i] * bb[jj];
    }
    __syncthreads();
  }

  float bias[8];
  #pragma unroll
  for (int jj = 0; jj < 8; ++jj) {
    int n = n0 + ((jj < 4) ? (tx * 4 + jj) : (64 + tx * 4 + (jj - 4)));
    bias[jj] = (n < 512) ? (bihf[n] + bhhf[n]) : (bihb[n - 512] + bhhb[n - 512]);
  }
  #pragma unroll
  for (int i = 0; i < 8; ++i) {
    int gm = m0 + ty * 8 + i;
    if (gm >= VOCAB) continue;
    float4 v0 = make_float4(acc[i][0] + bias[0], acc[i][1] + bias[1],
                            acc[i][2] + bias[2], acc[i][3] + bias[3]);
    float4 v1 = make_float4(acc[i][4] + bias[4], acc[i][5] + bias[5],
                            acc[i][6] + bias[6], acc[i][7] + bias[7]);
    *(float4*)(embW + (size_t)gm * NCOL + n0 + tx * 4) = v0;
    *(float4*)(embW + (size_t)gm * NCOL + n0 + 64 + tx * 4) = v1;
  }
}

// ---------------------------------------------------------------------------
// Kernel 2: masked LSTM recurrence. RESTORED R1 — the proven optimum
// (393.6us measured). Structural-floor ledger (R2-R8, all falsified):
//  - chain add/remove (R2/R3/R4): removals null, additions cost 1:1 -> the
//    floor is not in the instruction stream.
//  - weight residency (R0/R1/R5): weights are AGPR-resident via "+v" pins;
//    forcing "+a" spills catastrophically.
//  - lockstep waves/SIMD 2->4 (R6/R7): idle ~1000cyc/step is constant —
//    same-block waves share the barrier and cannot fill each other.
//  - in-stream ILP, 2 jobs/block (R8): fills ~20% idle (1476 vs 1845
//    cyc/batch-step) but halves CU parallelism; wall = len-512 block.
// Constraint set: one recurrence = one block (>=512 thr for register-resident
// weights; per-step all-to-all h -> one barrier domain); 256 jobs = 256 CUs.
// ---------------------------------------------------------------------------
#define REP8(M) M(0) M(1) M(2) M(3) M(4) M(5) M(6) M(7)
#define REP8G(M,G) M(G,0) M(G,1) M(G,2) M(G,3) M(G,4) M(G,5) M(G,6) M(G,7)

__global__ __launch_bounds__(512)
__attribute__((amdgpu_waves_per_eu(2, 2)))
void lstm_rec(
    const int* __restrict__ pad_seq, const int* __restrict__ lens,
    const float* __restrict__ Whh_f, const float* __restrict__ Whh_b,
    const float* __restrict__ embW, const float* __restrict__ W_lab,
    float* __restrict__ e_part) {
  const int dir = blockIdx.x & 1;
  const int b   = blockIdx.x >> 1;
  const int tid = threadIdx.x;
  const int j   = tid >> 2;      // hidden unit 0..127
  const int q   = tid & 3;       // K-quarter / gate owner 0..3
  const int parity = q & 1;
  const int half   = (q >> 1) & 1;

  __shared__ float ring[8][4][36];   // [slot][chunk][32 + 4 pad]
  __shared__ float wls[4][132];      // W_lab cols for MY direction, padded
  __shared__ int   tok[TMAX];

  tok[tid] = pad_seq[b * TMAX + tid];
  wls[tid >> 7][tid & 127] = W_lab[(tid >> 7) * DIM + dir * HID + (tid & 127)];
  if (tid < 144) ((float*)ring)[tid] = 0.f;    // slot 0 = h(-1) = 0

  const int len = lens[b];
  const float* __restrict__ Whh = dir ? Whh_b : Whh_f;

  // W_hh: 4 gate rows x 32 cols = 128 pinned scalars
  const float4* wr0 = (const float4*)(Whh + (size_t)(0 * HID + j) * HID + 32 * q);
  const float4* wr1 = (const float4*)(Whh + (size_t)(1 * HID + j) * HID + 32 * q);
  const float4* wr2 = (const float4*)(Whh + (size_t)(2 * HID + j) * HID + 32 * q);
  const float4* wr3 = (const float4*)(Whh + (size_t)(3 * HID + j) * HID + 32 * q);
#define DECLW(G,I)                                                      \
  float w##G##_##I##_0, w##G##_##I##_1, w##G##_##I##_2, w##G##_##I##_3; \
  { float4 t = wr##G[I];                                                \
    w##G##_##I##_0 = t.x; w##G##_##I##_1 = t.y;                         \
    w##G##_##I##_2 = t.z; w##G##_##I##_3 = t.w; }                       \
  asm volatile("" : "+v"(w##G##_##I##_0));                              \
  asm volatile("" : "+v"(w##G##_##I##_1));                              \
  asm volatile("" : "+v"(w##G##_##I##_2));                              \
  asm volatile("" : "+v"(w##G##_##I##_3));
  REP8G(DECLW,0) REP8G(DECLW,1) REP8G(DECLW,2) REP8G(DECLW,3)
#undef DECLW

// loop-carried re-pin: keeps weights register/AGPR-resident across the loop.
#define KEEPW(G,I)                                                      \
  asm volatile("" : "+v"(w##G##_##I##_0), "+v"(w##G##_##I##_1),         \
                    "+v"(w##G##_##I##_2), "+v"(w##G##_##I##_3));

  float c = 0.f;
  const float ascale = (q == 2) ? 2.f : 1.f;     // tanh(x)=2*sig(2x)-1 for g
  const float* __restrict__ ecol = embW + dir * G4 + (q * HID + j);
  float* __restrict__ ep = e_part + (size_t)(dir * BATCH + b) * TMAX * 4;

  bar_lds();

  // batched x@Wih gathers for the next 8 steps (ride across lgkm-only
  // barriers; per-use vmcnt(N) waits)
  float xb0, xb1, xb2, xb3, xb4, xb5, xb6, xb7;
#define PRE(r) { const int ss = nbase + r; xb##r = 0.f;                 \
    if (ss < len) {                                                     \
      const int tt = dir ? (len - 1 - ss) : ss;                         \
      xb##r = ecol[(size_t)tok[tt] * NCOL]; } }
  { const int nbase = 0; REP8(PRE) }

#define MACC(G,I)                                         \
    a##G##0 = fmaf(hv##I.x, w##G##_##I##_0, a##G##0);     \
    a##G##1 = fmaf(hv##I.y, w##G##_##I##_1, a##G##1);     \
    a##G##2 = fmaf(hv##I.z, w##G##_##I##_2, a##G##2);     \
    a##G##3 = fmaf(hv##I.w, w##G##_##I##_3, a##G##3);

#define STEP(r, XW)                                                     \
  {                                                                     \
    const float4* h4 = (const float4*)&ring[r][q][0];                   \
    float4 hv0 = h4[0], hv1 = h4[1], hv2 = h4[2], hv3 = h4[3];          \
    float4 hv4 = h4[4], hv5 = h4[5], hv6 = h4[6], hv7 = h4[7];          \
    float a00=0.f,a01=0.f,a02=0.f,a03=0.f;                              \
    float a10=0.f,a11=0.f,a12=0.f,a13=0.f;                              \
    float a20=0.f,a21=0.f,a22=0.f,a23=0.f;                              \
    float a30=0.f,a31=0.f,a32=0.f,a33=0.f;                              \
    REP8G(MACC,0) REP8G(MACC,1) REP8G(MACC,2) REP8G(MACC,3)             \
    const float p0 = (a00+a01)+(a02+a03);                               \
    const float p1 = (a10+a11)+(a12+a13);                               \
    const float p2 = (a20+a21)+(a22+a23);                               \
    const float p3 = (a30+a31)+(a32+a33);                               \
    /* quad transpose-reduce via DPP: thread q ends with gate q's total */ \
    const float klo = parity ? p1 : p0, slo = parity ? p0 : p1;         \
    const float khi = parity ? p3 : p2, shi = parity ? p2 : p3;         \
    const float alo = klo + dpp_xor1(slo);                              \
    const float ahi = khi + dpp_xor1(shi);                              \
    const float kb = half ? ahi : alo, sb = half ? alo : ahi;           \
    const float tot = kb + dpp_xor2(sb);                                \
    const float aa = tot + (XW);                                        \
    const float sg = 1.f / (1.f + __expf(-ascale * aa));                \
    const float act = (q == 2) ? (2.f * sg - 1.f) : sg;                 \
    /* quad exchange of ACTIVATED gates via DPP */                      \
    const float e1 = dpp_xor1(act);                                     \
    const float e2 = dpp_xor2(act);                                     \
    const float e3 = dpp_xor2(e1);                                      \
    const float ev  = parity ? e1 : act, od  = parity ? act : e1;       \
    const float ev2 = parity ? e3 : e2,  od2 = parity ? e2 : e3;        \
    const float ig = half ? ev2 : ev, fg = half ? od2 : od;             \
    const float gt = half ? ev : ev2, og = half ? od : od2;             \
    c = fg * c + ig * gt;                                               \
    const float s2 = 1.f / (1.f + __expf(-2.f * c));                    \
    const float hh = og * (2.f * s2 - 1.f);                             \
    if (q == 0) ring[(r + 1) & 7][j >> 5][j & 31] = hh;                 \
    bar_lds();                                                          \
  }

  for (int s0 = 0; s0 < len; s0 += 8) {
    REP8G(KEEPW,0) REP8G(KEEPW,1) REP8G(KEEPW,2) REP8G(KEEPW,3)
    const int cnt = (len - s0 < 8) ? (len - s0) : 8;   // block-uniform
    STEP(0, xb0)
    if (cnt > 1) STEP(1, xb1)
    if (cnt > 2) STEP(2, xb2)
    if (cnt > 3) STEP(3, xb3)
    if (cnt > 4) STEP(4, xb4)
    if (cnt > 5) STEP(5, xb5)
    if (cnt > 6) STEP(6, xb6)
    if (cnt > 7) STEP(7, xb7)
    // prefetch next group's gathers (no drain: they ride across barriers)
    { const int nbase = s0 + 8; REP8(PRE) }
    // emission partials for this group: (r,l,sub) = 8x4x16 = 512 threads
    {
      const int r = tid >> 6, l = (tid >> 4) & 3, sub = tid & 15;
      if (r < cnt) {                        // wave-uniform (r const per wave)
        const float4* hp = (const float4*)&ring[(r + 1) & 7][sub >> 2][8 * (sub & 3)];
        const float4 h0 = hp[0], h1 = hp[1];
        const float4* wp = (const float4*)&wls[l][8 * sub];
        const float4 u0 = wp[0], u1 = wp[1];
        float d = h0.x*u0.x + h0.y*u0.y + h0.z*u0.z + h0.w*u0.w
                + h1.x*u1.x + h1.y*u1.y + h1.z*u1.z + h1.w*u1.w;
        d += dpp_xor1(d); d += dpp_xor2(d);
        d += __shfl_xor(d, 4); d += __shfl_xor(d, 8);
        if (sub == 0) {
          const int ss = s0 + r;
          const int tt = dir ? (len - 1 - ss) : ss;
          ep[tt * 4 + l] = d;
        }
      }
    }
    bar_lds();
  }
#undef STEP
#undef MACC
#undef PRE
#undef KEEPW
}

// ---------------------------------------------------------------------------
// Kernel 3: Viterbi (emissions pre-reduced into e_part by lstm_rec).
// ---------------------------------------------------------------------------
__global__ __launch_bounds__(512) void viterbi_k(
    const int* __restrict__ lens, const float* __restrict__ e_part,
    const float* __restrict__ b_lab, const float* __restrict__ trans,
    const float* __restrict__ from_BOS, const float* __restrict__ to_EOS,
    int* __restrict__ out) {
  const int b = blockIdx.x;
  const int tid = threadIdx.x;
  __shared__ float sc[TMAX][4];
  __shared__ unsigned btm[TMAX];
  __shared__ int labs[TMAX];
  const int len = lens[b];

  if (tid < len) {
    const float4 f  = *(const float4*)(e_part + ((size_t)b * TMAX + tid) * 4);
    const float4 g2 = *(const float4*)(e_part + ((size_t)(BATCH + b) * TMAX + tid) * 4);
    const float4 bl = *(const float4*)b_lab;
    sc[tid][0] = f.x + g2.x + bl.x;
    sc[tid][1] = f.y + g2.y + bl.y;
    sc[tid][2] = f.z + g2.z + bl.z;
    sc[tid][3] = f.w + g2.w + bl.w;
  }
  __syncthreads();

  // --- DP: lanes 0..3 of wave 0, lane l owns cur-label l ---
  if (tid < 4) {
    const int l = tid;
    float trc0 = trans[0 * 4 + l], trc1 = trans[1 * 4 + l];
    float trc2 = trans[2 * 4 + l], trc3 = trans[3 * 4 + l];
    float best = from_BOS[l] + sc[0][l];
    float e_next = sc[1][l];
    for (int ti = 1; ti < len; ++ti) {
      const float e = e_next;
      e_next = sc[(ti + 1 < TMAX) ? ti + 1 : ti][l];
      const float b0 = dpp_bc0(best);
      const float b1 = dpp_bc1(best);
      const float b2 = dpp_bc2(best);
      const float b3 = dpp_bc3(best);
      // reference add order: (best[p] + e[cur]) + trans[p][cur]; first-max
      float m = (b0 + e) + trc0; int arg = 0;
      float v;
      v = (b1 + e) + trc1; if (v > m) { m = v; arg = 1; }
      v = (b2 + e) + trc2; if (v > m) { m = v; arg = 2; }
      v = (b3 + e) + trc3; if (v > m) { m = v; arg = 3; }
      best = m;
      unsigned av = ((unsigned)arg) << (8 * l);
      av |= dpp_xor1u(av);
      av |= dpp_xor2u(av);
      if (l == 0) btm[ti] = av;
    }
    const float f0 = dpp_bc0(best) + to_EOS[0];
    const float f1 = dpp_bc1(best) + to_EOS[1];
    const float f2 = dpp_bc2(best) + to_EOS[2];
    const float f3 = dpp_bc3(best) + to_EOS[3];
    if (l == 0) {
      float m = f0; int last = 0;
      if (f1 > m) { m = f1; last = 1; }
      if (f2 > m) { m = f2; last = 2; }
      if (f3 > m) { m = f3; last = 3; }
      labs[len - 1] = last;
      int cur = last;
      #pragma unroll 4
      for (int ti = len - 2; ti >= 0; --ti) {
        cur = (int)((btm[ti + 1] >> (8 * cur)) & 255u);
        labs[ti] = cur;
      }
    }
  }
  __syncthreads();
  out[b * TMAX + tid] = (tid < len) ? labs[tid] : 0;
}

// ---------------------------------------------------------------------------
extern "C" void kernel_launch(void* const* d_in, const int* in_sizes, int n_in,
                              void* d_out, int out_size, void* d_ws, size_t ws_size,
                              hipStream_t stream) {
  const int*   pad_seq  = (const int*)d_in[0];
  const int*   lens     = (const int*)d_in[1];
  const float* emb      = (const float*)d_in[2];
  const float* W_ih_f   = (const float*)d_in[3];
  const float* W_hh_f   = (const float*)d_in[4];
  const float* b_ih_f   = (const float*)d_in[5];
  const float* b_hh_f   = (const float*)d_in[6];
  const float* W_ih_b   = (const float*)d_in[7];
  const float* W_hh_b   = (const float*)d_in[8];
  const float* b_ih_b   = (const float*)d_in[9];
  const float* b_hh_b   = (const float*)d_in[10];
  const float* W_lab    = (const float*)d_in[11];
  const float* b_lab    = (const float*)d_in[12];
  const float* trans    = (const float*)d_in[13];
  const float* from_BOS = (const float*)d_in[14];
  const float* to_EOS   = (const float*)d_in[15];
  int* out = (int*)d_out;

  float* embW   = (float*)d_ws;                      // [8000][1024] = 32.8 MB
  float* e_part = embW + (size_t)VOCAB * NCOL;       // [2][B][T][4] = 2 MB

  embw_gemm<<<dim3(63, 8), 256, 0, stream>>>(emb, W_ih_f, W_ih_b,
                                             b_ih_f, b_hh_f, b_ih_b, b_hh_b, embW);
  lstm_rec<<<dim3(2 * BATCH), 512, 0, stream>>>(pad_seq, lens, W_hh_f, W_hh_b,
                                                embW, W_lab, e_part);
  viterbi_k<<<dim3(BATCH), 512, 0, stream>>>(lens, e_part, b_lab, trans,
                                             from_BOS, to_EOS, out);
}